// Round 6
// baseline (495.634 us; speedup 1.0000x reference)
//
#include <hip/hip_runtime.h>
#include <hip/hip_bf16.h>

// ---------------------------------------------------------------------------
// AttentionBase: out = softmax((in@Wq^T+bq)*ds @ (mem@Wk^T+bk)^T) @ (mem@Wv^T+bv) @ Wo^T + bo
// B=8, S=2048, C=1024. All matmuls bf16 MFMA gemm_bt.
// Quad-buffered BK=32 K-pipeline with PHASE-SPLIT schedule (T3+T4+T5):
//   per slice t (2 phases):
//     P0: stageA(t+3); ds_read af-lo + bf; barrier; setprio1; MFMA lo; setprio0; barrier
//     P1: stageB(t+3); ds_read af-hi;      barrier; setprio1; MFMA hi; setprio0;
//         vmcnt(2*LT) [never 0]; barrier   <- syncs slice t+1 one barrier early
// Granule swizzle (g ^= (row>>1)&3, 16B granules), both-sides (pre-swizzled
// global source for global_load_lds + swizzled ds_read) -> 0 bank conflicts.
// PV row-sums via ones-operand MFMA. d_out doubles as scratch (Vt | inb).
// ---------------------------------------------------------------------------

typedef __attribute__((ext_vector_type(8))) short short8;   // 8 bf16 = 4 VGPRs
typedef __attribute__((ext_vector_type(4))) float f32x4;

static __device__ __forceinline__ unsigned short f2bf(float f) {
  union { float f; unsigned u; } x; x.f = f;
  unsigned r = x.u + 0x7FFFu + ((x.u >> 16) & 1u);   // round-to-nearest-even
  return (unsigned short)(r >> 16);
}

static __device__ __forceinline__ void g2l16(const void* g, void* l) {
  __builtin_amdgcn_global_load_lds(
      (const __attribute__((address_space(1))) void*)g,
      (__attribute__((address_space(3))) void*)l, 16, 0, 0);
}

template <int N> static __device__ __forceinline__ void vmw() {
  if constexpr (N == 8)      asm volatile("s_waitcnt vmcnt(8)" ::: "memory");
  else if constexpr (N == 6) asm volatile("s_waitcnt vmcnt(6)" ::: "memory");
  else if constexpr (N == 4) asm volatile("s_waitcnt vmcnt(4)" ::: "memory");
  else if constexpr (N == 3) asm volatile("s_waitcnt vmcnt(3)" ::: "memory");
  else                       asm volatile("s_waitcnt vmcnt(0)" ::: "memory");
}

// f32 -> bf16 conversion, float4/ushort4 vectorized, grid-stride
__global__ __launch_bounds__(256) void cvt_kernel(const float* __restrict__ in,
                                                  unsigned short* __restrict__ out,
                                                  long long n4) {
  long long i = (long long)blockIdx.x * 256 + threadIdx.x;
  const long long stride = (long long)gridDim.x * 256;
  for (; i < n4; i += stride) {
    float4 v = ((const float4*)in)[i];
    ushort4 o;
    o.x = f2bf(v.x); o.y = f2bf(v.y); o.z = f2bf(v.z); o.w = f2bf(v.w);
    ((ushort4*)out)[i] = o;
  }
}

// all four C*C weights in one launch; blockIdx.y selects the matrix
__global__ __launch_bounds__(256) void wcvt_kernel(
    const float* __restrict__ w0, const float* __restrict__ w1,
    const float* __restrict__ w2, const float* __restrict__ w3,
    unsigned short* __restrict__ o0, unsigned short* __restrict__ o1,
    unsigned short* __restrict__ o2, unsigned short* __restrict__ o3,
    int n4) {
  const float* src; unsigned short* dst;
  switch (blockIdx.y) {
    case 0: src = w0; dst = o0; break;
    case 1: src = w1; dst = o1; break;
    case 2: src = w2; dst = o2; break;
    default: src = w3; dst = o3; break;
  }
  int i = blockIdx.x * 256 + threadIdx.x;
  const int stride = gridDim.x * 256;
  for (; i < n4; i += stride) {
    float4 v = ((const float4*)src)[i];
    ushort4 o;
    o.x = f2bf(v.x); o.y = f2bf(v.y); o.z = f2bf(v.z); o.w = f2bf(v.w);
    ((ushort4*)dst)[i] = o;
  }
}

#define EPI_BF16 0
#define EPI_BF16_TRANS 1
#define EPI_EXP 2
#define EPI_PV 3
#define EPI_F32 4

// D[m][n] = epilogue(sum_k A[m][k]*B[n][k] (+bias[n]) (*scale)), batched via z.
template <int BM, int BN, int EPI, bool HAS_BIAS>
__global__ __launch_bounds__(512, 2) void gemm_kernel(
    const unsigned short* __restrict__ A, const unsigned short* __restrict__ B,
    const float* __restrict__ bias, void* __restrict__ Dv,
    int K, int lda, int ldb, int ldd,
    long long sA, long long sB, long long sD, float scale) {
  constexpr int WM = 2, WN = 4;
  constexpr int MF = BM / (WM * 16);    // m-frags per wave
  constexpr int NF = BN / (WN * 16);    // n-frags per wave
  constexpr int MH = MF / 2;            // frags per phase
  constexpr int LA = BM / 128;          // g2l16 per thread per A slice
  constexpr int LB = BN / 128;
  constexpr int LT = LA + LB;
  constexpr int ASL = BM * 32;          // slice elements
  constexpr int BSL = BN * 32;

  // ---- T1: chunked XCD swizzle over the flattened grid (nwg % 8 == 0) ----
  int lin = blockIdx.x + gridDim.x * (blockIdx.y + gridDim.y * blockIdx.z);
  const int nwg = gridDim.x * gridDim.y * gridDim.z;
  lin = (lin & 7) * (nwg >> 3) + (lin >> 3);
  const int bx = lin % gridDim.x;
  int rem0 = lin / gridDim.x;
  const int by = rem0 % gridDim.y;
  const int bz = rem0 / gridDim.y;

  const int bm = bx * BM;
  const int bn = by * BN;
  const int tid = threadIdx.x;
  const int lane = tid & 63;
  const int wid = tid >> 6;
  const int wr = (wid / WN) * (BM / WM);
  const int wc = (wid % WN) * (BN / WN);
  const int fr = lane & 15;
  const int hi = lane >> 4;
  const int rg = ((hi ^ ((fr >> 1) & 3)) << 3);   // swizzled read granule (elems)

  __shared__ __align__(16) unsigned short As[4 * ASL];
  __shared__ __align__(16) unsigned short Bs[4 * BSL];

  f32x4 acc[MF][NF];
#pragma unroll
  for (int m = 0; m < MF; ++m)
#pragma unroll
    for (int n = 0; n < NF; ++n) acc[m][n] = (f32x4){0.f, 0.f, 0.f, 0.f};

  f32x4 asum[MF];          // PV: row-sums via ones-operand MFMA
  short8 ones;
#pragma unroll
  for (int m = 0; m < MF; ++m) asum[m] = (f32x4){0.f, 0.f, 0.f, 0.f};
#pragma unroll
  for (int j = 0; j < 8; ++j) ones[j] = (short)0x3F80;  // bf16 1.0

  // ---- stage pointers (advance +32 elems per stage call; no in-loop muls) --
  const unsigned short* apt[LA];
  const unsigned short* bpt[LB];
#pragma unroll
  for (int i = 0; i < LA; ++i) {
    const int slot = i * 512 + tid;
    const int row = slot >> 2;
    const int g = (slot & 3) ^ ((row >> 1) & 3);
    apt[i] = A + (long long)bz * sA + (long long)(bm + row) * lda + g * 8;
  }
#pragma unroll
  for (int i = 0; i < LB; ++i) {
    const int slot = i * 512 + tid;
    const int row = slot >> 2;
    const int g = (slot & 3) ^ ((row >> 1) & 3);
    bpt[i] = B + (long long)bz * sB + (long long)(bn + row) * ldb + g * 8;
  }
  auto stageA = [&](int buf) {
#pragma unroll
    for (int i = 0; i < LA; ++i) {
      g2l16(apt[i], &As[buf * ASL + (i * 512 + tid) * 8]);
      apt[i] += 32;
    }
  };
  auto stageB = [&](int buf) {
#pragma unroll
    for (int i = 0; i < LB; ++i) {
      g2l16(bpt[i], &Bs[buf * BSL + (i * 512 + tid) * 8]);
      bpt[i] += 32;
    }
  };

  const int NT = K >> 5;   // K-slices of 32

  // ---- prologue: fill pipeline 3 slices deep, sync slice 0 ----
  stageA(0); stageB(0);
  stageA(1); stageB(1);
  stageA(2); stageB(2);
  vmw<2 * LT>();                         // drain slice 0, keep 1,2 in flight
  __builtin_amdgcn_s_barrier();
  __builtin_amdgcn_sched_barrier(0);

  for (int t = 0; t < NT; ++t) {
    const int buf = t & 3;
    const int nbuf = (t + 3) & 3;
    const bool st = (t + 3) < NT;

    // ======== phase 0: stage A(t+3) | read af-lo + bf | MFMA lo ========
    if (st) stageA(nbuf);
    short8 af0[MH], bf[NF];
#pragma unroll
    for (int m = 0; m < MH; ++m)
      af0[m] = *(const short8*)&As[buf * ASL + (wr + m * 16 + fr) * 32 + rg];
#pragma unroll
    for (int n = 0; n < NF; ++n)
      bf[n] = *(const short8*)&Bs[buf * BSL + (wc + n * 16 + fr) * 32 + rg];
    __builtin_amdgcn_sched_barrier(0);
    __builtin_amdgcn_s_barrier();
    __builtin_amdgcn_sched_barrier(0);
    __builtin_amdgcn_s_setprio(1);
#pragma unroll
    for (int m = 0; m < MH; ++m)
#pragma unroll
      for (int n = 0; n < NF; ++n)
        acc[m][n] = __builtin_amdgcn_mfma_f32_16x16x32_bf16(af0[m], bf[n],
                                                            acc[m][n], 0, 0, 0);
    if (EPI == EPI_PV) {
#pragma unroll
      for (int m = 0; m < MH; ++m)
        asum[m] = __builtin_amdgcn_mfma_f32_16x16x32_bf16(af0[m], ones,
                                                          asum[m], 0, 0, 0);
    }
    __builtin_amdgcn_s_setprio(0);
    __builtin_amdgcn_sched_barrier(0);
    __builtin_amdgcn_s_barrier();
    __builtin_amdgcn_sched_barrier(0);

    // ======== phase 1: stage B(t+3) | read af-hi | MFMA hi ========
    if (st) stageB(nbuf);
    short8 af1[MH];
#pragma unroll
    for (int m = 0; m < MH; ++m)
      af1[m] = *(const short8*)&As[buf * ASL + (wr + (MH + m) * 16 + fr) * 32 + rg];
    __builtin_amdgcn_sched_barrier(0);
    __builtin_amdgcn_s_barrier();
    __builtin_amdgcn_sched_barrier(0);
    __builtin_amdgcn_s_setprio(1);
#pragma unroll
    for (int m = 0; m < MH; ++m)
#pragma unroll
      for (int n = 0; n < NF; ++n)
        acc[MH + m][n] = __builtin_amdgcn_mfma_f32_16x16x32_bf16(af1[m], bf[n],
                                                                 acc[MH + m][n], 0, 0, 0);
    if (EPI == EPI_PV) {
#pragma unroll
      for (int m = 0; m < MH; ++m)
        asum[MH + m] = __builtin_amdgcn_mfma_f32_16x16x32_bf16(af1[m], ones,
                                                               asum[MH + m], 0, 0, 0);
    }
    __builtin_amdgcn_s_setprio(0);
    __builtin_amdgcn_sched_barrier(0);
    // ---- slice-end: sync slice t+1 one barrier before its reads ----
    if (t + 3 < NT)       vmw<2 * LT>();   // never 0 in steady state
    else if (t + 2 < NT)  vmw<LT>();
    else if (t + 1 < NT)  vmw<0>();
    __builtin_amdgcn_s_barrier();
    __builtin_amdgcn_sched_barrier(0);
  }

  // ---- epilogue: C/D frag layout col=lane&15, row=(lane>>4)*4+j ----
  const int cr = hi * 4;
  const int cc = fr;
#pragma unroll
  for (int m = 0; m < MF; ++m) {
    const int row0 = bm + wr + m * 16 + cr;
#pragma unroll
    for (int n = 0; n < NF; ++n) {
      const int col = bn + wc + n * 16 + cc;
      const float bv = HAS_BIAS ? bias[col] : 0.f;
      if (EPI == EPI_F32) {
        float* D = (float*)Dv + (long long)bz * sD;
#pragma unroll
        for (int j = 0; j < 4; ++j)
          D[(long long)(row0 + j) * ldd + col] = acc[m][n][j] + bv;
      } else if (EPI == EPI_BF16) {
        unsigned short* D = (unsigned short*)Dv + (long long)bz * sD;
#pragma unroll
        for (int j = 0; j < 4; ++j)
          D[(long long)(row0 + j) * ldd + col] = f2bf((acc[m][n][j] + bv) * scale);
      } else if (EPI == EPI_BF16_TRANS) {
        unsigned short* D = (unsigned short*)Dv + (long long)bz * sD;
        ushort4 pk;
        pk.x = f2bf((acc[m][n][0] + bv) * scale);
        pk.y = f2bf((acc[m][n][1] + bv) * scale);
        pk.z = f2bf((acc[m][n][2] + bv) * scale);
        pk.w = f2bf((acc[m][n][3] + bv) * scale);
        *(ushort4*)&D[(long long)col * ldd + row0] = pk;
      } else if (EPI == EPI_EXP) {
        unsigned short* D = (unsigned short*)Dv + (long long)bz * sD;
#pragma unroll
        for (int j = 0; j < 4; ++j)
          D[(long long)(row0 + j) * ldd + col] = f2bf(__expf(acc[m][n][j]));
      } else {  // EPI_PV: normalize by MFMA-computed row-sum
        unsigned short* D = (unsigned short*)Dv + (long long)bz * sD;
#pragma unroll
        for (int j = 0; j < 4; ++j) {
          const float li = 1.f / asum[m][j];
          D[(long long)(row0 + j) * ldd + col] = f2bf(acc[m][n][j] * li);
        }
      }
    }
  }
}

extern "C" void kernel_launch(void* const* d_in, const int* in_sizes, int n_in,
                              void* d_out, int out_size, void* d_ws, size_t ws_size,
                              hipStream_t stream) {
  (void)in_sizes; (void)n_in; (void)out_size;
  const float* input  = (const float*)d_in[0];
  const float* memory = (const float*)d_in[1];
  const float* Wq = (const float*)d_in[2];
  const float* bq = (const float*)d_in[3];
  const float* Wk = (const float*)d_in[4];
  const float* bk = (const float*)d_in[5];
  const float* Wv = (const float*)d_in[6];
  const float* bv = (const float*)d_in[7];
  const float* Wo = (const float*)d_in[8];
  const float* bo = (const float*)d_in[9];
  float* out = (float*)d_out;

  const int S = 2048, C = 1024;
  const int CB = 4;                                // batches per attention chunk
  const long long BS = 16384;                      // 8 * 2048
  const long long N_IN = BS * C;                   // 16,777,216
  const long long N_W  = (long long)C * C;         // 1,048,576

  // ---- workspace layout (256B aligned), ~109 MiB ----
  char* p = (char*)d_ws;
  auto alloc = [&](size_t bytes) {
    char* r = p;
    p += (bytes + 255) & ~(size_t)255;
    return r;
  };
  unsigned short* wqb  = (unsigned short*)alloc(N_W * 2);
  unsigned short* wkb  = (unsigned short*)alloc(N_W * 2);
  unsigned short* wvb  = (unsigned short*)alloc(N_W * 2);
  unsigned short* wob  = (unsigned short*)alloc(N_W * 2);
  unsigned short* Qb   = (unsigned short*)alloc(N_IN * 2);   // [16384][1024]; later sel
  unsigned short* Kb   = (unsigned short*)alloc(N_IN * 2);   // [16384][1024]
  unsigned short* Xb   = (unsigned short*)alloc(N_IN * 2);   // memb, then Pt
  if ((size_t)(p - (char*)d_ws) > ws_size) return;

  // d_out scratch: [Vt bf16 16M | inb bf16 16M] = exactly 64 MiB
  unsigned short* Vt  = (unsigned short*)d_out;          // [1024][16384]
  unsigned short* inb = (unsigned short*)d_out + N_IN;   // [16384][1024]
  unsigned short* memb = Xb;
  unsigned short* Pt   = Xb;                             // alias after memb dead

  // ---- f32 -> bf16 ----
  wcvt_kernel<<<dim3(256, 4, 1), 256, 0, stream>>>(Wq, Wk, Wv, Wo,
                                                   wqb, wkb, wvb, wob,
                                                   (int)(N_W / 4));
  cvt_kernel<<<2048, 256, 0, stream>>>(memory, memb, N_IN / 4);
  cvt_kernel<<<2048, 256, 0, stream>>>(input,  inb,  N_IN / 4);

  const float depth_scale = 0.03125f;  // 1024^-0.5

  // ---- projections: 256x256 tile, grid 256 blocks (1/CU), 512 thr ----
  gemm_kernel<256, 256, EPI_BF16, true><<<dim3(64, 4, 1), 512, 0, stream>>>(
      memb, wkb, bk, Kb, C, C, C, C, 0, 0, 0, 1.0f);
  gemm_kernel<256, 256, EPI_BF16_TRANS, true><<<dim3(64, 4, 1), 512, 0, stream>>>(
      memb, wvb, bv, Vt, C, C, C, (int)BS, 0, 0, 0, 1.0f);
  gemm_kernel<256, 256, EPI_BF16, true><<<dim3(64, 4, 1), 512, 0, stream>>>(
      inb, wqb, bq, Qb, C, C, C, C, 0, 0, 0, depth_scale);

  // ---- attention, CB=4 batches at a time (memb dead -> Pt) ----
  for (int c = 0; c < 8 / CB; ++c) {
    const long long qoff = (long long)c * CB * S * C;
    // P~ = exp(Q[b] @ K[b]^T) -> bf16 [CB*2048][2048], grid (8,8,4)=256
    gemm_kernel<256, 256, EPI_EXP, false><<<dim3(8, 8, CB), 512, 0, stream>>>(
        Qb + qoff, Kb + qoff, nullptr, Pt,
        C, C, C, S, (long long)S * C, (long long)S * C, (long long)S * S, 1.0f);
    // sel[b] = (P~ @ V[b]) / rowsum(P~) -> bf16 over dead Q rows
    // 128x256 tile, grid (16,4,4)=256
    gemm_kernel<128, 256, EPI_PV, false><<<dim3(16, 4, CB), 512, 0, stream>>>(
        Pt, Vt + (long long)c * CB * S, nullptr, Qb + qoff,
        S, S, (int)BS, C, (long long)S * S, (long long)S, (long long)S * C, 1.0f);
  }

  // ---- out = sel @ Wo^T + bo -> f32 d_out (overwrites Vt/inb scratch) ----
  gemm_kernel<256, 256, EPI_F32, true><<<dim3(64, 4, 1), 512, 0, stream>>>(
      Qb, wob, bo, out, C, C, C, C, 0, 0, 0, 1.0f);
}

// Round 7
// 442.034 us; speedup vs baseline: 1.1213x; 1.1213x over previous
//
#include <hip/hip_runtime.h>
#include <hip/hip_bf16.h>

// ---------------------------------------------------------------------------
// AttentionBase: out = softmax((in@Wq^T+bq)*ds @ (mem@Wk^T+bk)^T) @ (mem@Wv^T+bv) @ Wo^T + bo
// B=8, S=2048, C=1024. All matmuls bf16 MFMA gemm_bt.
// Quad-buffered BK=32 K-pipeline; two schedule variants (A/B this round):
//  PIPE (r5 control): per slice [stage t+3 | read all | MFMA all | vmcnt(2LT) | bar]
//  PHASE (m201-style, minimal pinning): per slice
//    ph0: stageA(t+3); read af-lo+bf; bar; prio1; MFMA lo; prio0; bar
//    ph1: stageB(t+3); read af-hi;    bar; prio1; MFMA hi; prio0; vmcnt(2LT); bar
//    single sched_barrier(0) at the slice boundary only (the "memory" clobber
//    on the vmcnt asm fences LDS/VMEM motion; intra-slice motion is safe).
// Granule swizzle (g ^= (row>>1)&3, 16B granules) both-sides -> 0 conflicts.
// PV row-sums via ones-operand MFMA. d_out doubles as scratch (Vt | inb).
// ---------------------------------------------------------------------------

typedef __attribute__((ext_vector_type(8))) short short8;   // 8 bf16 = 4 VGPRs
typedef __attribute__((ext_vector_type(4))) float f32x4;

static __device__ __forceinline__ unsigned short f2bf(float f) {
  union { float f; unsigned u; } x; x.f = f;
  unsigned r = x.u + 0x7FFFu + ((x.u >> 16) & 1u);   // round-to-nearest-even
  return (unsigned short)(r >> 16);
}

static __device__ __forceinline__ void g2l16(const void* g, void* l) {
  __builtin_amdgcn_global_load_lds(
      (const __attribute__((address_space(1))) void*)g,
      (__attribute__((address_space(3))) void*)l, 16, 0, 0);
}

template <int N> static __device__ __forceinline__ void vmw() {
  if constexpr (N == 8)      asm volatile("s_waitcnt vmcnt(8)" ::: "memory");
  else if constexpr (N == 6) asm volatile("s_waitcnt vmcnt(6)" ::: "memory");
  else if constexpr (N == 4) asm volatile("s_waitcnt vmcnt(4)" ::: "memory");
  else if constexpr (N == 3) asm volatile("s_waitcnt vmcnt(3)" ::: "memory");
  else                       asm volatile("s_waitcnt vmcnt(0)" ::: "memory");
}

// f32 -> bf16: input & memory in one launch (blockIdx.y selects)
__global__ __launch_bounds__(256) void cvt2_kernel(const float* __restrict__ s0,
                                                   const float* __restrict__ s1,
                                                   unsigned short* __restrict__ o0,
                                                   unsigned short* __restrict__ o1,
                                                   long long n4) {
  const float* src = blockIdx.y ? s1 : s0;
  unsigned short* dst = blockIdx.y ? o1 : o0;
  long long i = (long long)blockIdx.x * 256 + threadIdx.x;
  const long long stride = (long long)gridDim.x * 256;
  for (; i < n4; i += stride) {
    float4 v = ((const float4*)src)[i];
    ushort4 o;
    o.x = f2bf(v.x); o.y = f2bf(v.y); o.z = f2bf(v.z); o.w = f2bf(v.w);
    ((ushort4*)dst)[i] = o;
  }
}

// all four C*C weights in one launch; blockIdx.y selects the matrix
__global__ __launch_bounds__(256) void wcvt_kernel(
    const float* __restrict__ w0, const float* __restrict__ w1,
    const float* __restrict__ w2, const float* __restrict__ w3,
    unsigned short* __restrict__ o0, unsigned short* __restrict__ o1,
    unsigned short* __restrict__ o2, unsigned short* __restrict__ o3,
    int n4) {
  const float* src; unsigned short* dst;
  switch (blockIdx.y) {
    case 0: src = w0; dst = o0; break;
    case 1: src = w1; dst = o1; break;
    case 2: src = w2; dst = o2; break;
    default: src = w3; dst = o3; break;
  }
  int i = blockIdx.x * 256 + threadIdx.x;
  const int stride = gridDim.x * 256;
  for (; i < n4; i += stride) {
    float4 v = ((const float4*)src)[i];
    ushort4 o;
    o.x = f2bf(v.x); o.y = f2bf(v.y); o.z = f2bf(v.z); o.w = f2bf(v.w);
    ((ushort4*)dst)[i] = o;
  }
}

#define EPI_BF16 0
#define EPI_BF16_TRANS 1
#define EPI_EXP 2
#define EPI_PV 3
#define EPI_F32 4

// D[m][n] = epilogue(sum_k A[m][k]*B[n][k] (+bias[n]) (*scale)), batched via z.
template <int BM, int BN, int WM, int WN, int EPI, bool HAS_BIAS, bool PHASE>
__global__ __launch_bounds__(512, 2) void gemm_kernel(
    const unsigned short* __restrict__ A, const unsigned short* __restrict__ B,
    const float* __restrict__ bias, void* __restrict__ Dv,
    int K, int lda, int ldb, int ldd,
    long long sA, long long sB, long long sD, float scale) {
  constexpr int MF = BM / (WM * 16);    // m-frags per wave
  constexpr int NF = BN / (WN * 16);    // n-frags per wave
  constexpr int MH = MF / 2;            // frags per PHASE half
  constexpr int LA = BM / 128;          // g2l16 per thread per A slice
  constexpr int LB = BN / 128;
  constexpr int LT = LA + LB;
  constexpr int ASL = BM * 32;          // slice elements
  constexpr int BSL = BN * 32;

  // ---- T1: chunked XCD swizzle over the flattened grid (nwg % 8 == 0) ----
  int lin = blockIdx.x + gridDim.x * (blockIdx.y + gridDim.y * blockIdx.z);
  const int nwg = gridDim.x * gridDim.y * gridDim.z;
  lin = (lin & 7) * (nwg >> 3) + (lin >> 3);
  const int bx = lin % gridDim.x;
  int rem0 = lin / gridDim.x;
  const int by = rem0 % gridDim.y;
  const int bz = rem0 / gridDim.y;

  const int bm = bx * BM;
  const int bn = by * BN;
  const int tid = threadIdx.x;
  const int lane = tid & 63;
  const int wid = tid >> 6;
  const int wr = (wid / WN) * (BM / WM);
  const int wc = (wid % WN) * (BN / WN);
  const int fr = lane & 15;
  const int hi = lane >> 4;
  const int rg = ((hi ^ ((fr >> 1) & 3)) << 3);   // swizzled read granule (elems)

  __shared__ __align__(16) unsigned short As[4 * ASL];
  __shared__ __align__(16) unsigned short Bs[4 * BSL];

  f32x4 acc[MF][NF];
#pragma unroll
  for (int m = 0; m < MF; ++m)
#pragma unroll
    for (int n = 0; n < NF; ++n) acc[m][n] = (f32x4){0.f, 0.f, 0.f, 0.f};

  f32x4 asum[MF];          // PV: row-sums via ones-operand MFMA
  short8 ones;
#pragma unroll
  for (int m = 0; m < MF; ++m) asum[m] = (f32x4){0.f, 0.f, 0.f, 0.f};
#pragma unroll
  for (int j = 0; j < 8; ++j) ones[j] = (short)0x3F80;  // bf16 1.0

  // ---- stage pointers (advance +32 elems per stage call) ----
  const unsigned short* apt[LA];
  const unsigned short* bpt[LB];
#pragma unroll
  for (int i = 0; i < LA; ++i) {
    const int slot = i * 512 + tid;
    const int row = slot >> 2;
    const int g = (slot & 3) ^ ((row >> 1) & 3);
    apt[i] = A + (long long)bz * sA + (long long)(bm + row) * lda + g * 8;
  }
#pragma unroll
  for (int i = 0; i < LB; ++i) {
    const int slot = i * 512 + tid;
    const int row = slot >> 2;
    const int g = (slot & 3) ^ ((row >> 1) & 3);
    bpt[i] = B + (long long)bz * sB + (long long)(bn + row) * ldb + g * 8;
  }
  auto stageA = [&](int buf) {
#pragma unroll
    for (int i = 0; i < LA; ++i) {
      g2l16(apt[i], &As[buf * ASL + (i * 512 + tid) * 8]);
      apt[i] += 32;
    }
  };
  auto stageB = [&](int buf) {
#pragma unroll
    for (int i = 0; i < LB; ++i) {
      g2l16(bpt[i], &Bs[buf * BSL + (i * 512 + tid) * 8]);
      bpt[i] += 32;
    }
  };

  const int NT = K >> 5;   // K-slices of 32

  // ---- prologue: fill pipeline 3 slices deep, sync slice 0 ----
  stageA(0); stageB(0);
  stageA(1); stageB(1);
  stageA(2); stageB(2);
  vmw<2 * LT>();                         // drain slice 0, keep 1,2 in flight
  __builtin_amdgcn_s_barrier();
  __builtin_amdgcn_sched_barrier(0);

  for (int t = 0; t < NT; ++t) {
    const int buf = t & 3;
    const int nbuf = (t + 3) & 3;
    const bool st = (t + 3) < NT;
    short8 af[MF], bf[NF];

    if (PHASE) {
      // ======== phase 0: stage A(t+3) | read af-lo + bf | MFMA lo ========
      if (st) stageA(nbuf);
#pragma unroll
      for (int m = 0; m < MH; ++m)
        af[m] = *(const short8*)&As[buf * ASL + (wr + m * 16 + fr) * 32 + rg];
#pragma unroll
      for (int n = 0; n < NF; ++n)
        bf[n] = *(const short8*)&Bs[buf * BSL + (wc + n * 16 + fr) * 32 + rg];
      __builtin_amdgcn_s_barrier();
      __builtin_amdgcn_s_setprio(1);
#pragma unroll
      for (int m = 0; m < MH; ++m)
#pragma unroll
        for (int n = 0; n < NF; ++n)
          acc[m][n] = __builtin_amdgcn_mfma_f32_16x16x32_bf16(af[m], bf[n],
                                                              acc[m][n], 0, 0, 0);
      if (EPI == EPI_PV) {
#pragma unroll
        for (int m = 0; m < MH; ++m)
          asum[m] = __builtin_amdgcn_mfma_f32_16x16x32_bf16(af[m], ones,
                                                            asum[m], 0, 0, 0);
      }
      __builtin_amdgcn_s_setprio(0);
      __builtin_amdgcn_s_barrier();
      // ======== phase 1: stage B(t+3) | read af-hi | MFMA hi ========
      if (st) stageB(nbuf);
#pragma unroll
      for (int m = MH; m < MF; ++m)
        af[m] = *(const short8*)&As[buf * ASL + (wr + m * 16 + fr) * 32 + rg];
      __builtin_amdgcn_s_barrier();
      __builtin_amdgcn_s_setprio(1);
#pragma unroll
      for (int m = MH; m < MF; ++m)
#pragma unroll
        for (int n = 0; n < NF; ++n)
          acc[m][n] = __builtin_amdgcn_mfma_f32_16x16x32_bf16(af[m], bf[n],
                                                              acc[m][n], 0, 0, 0);
      if (EPI == EPI_PV) {
#pragma unroll
        for (int m = MH; m < MF; ++m)
          asum[m] = __builtin_amdgcn_mfma_f32_16x16x32_bf16(af[m], ones,
                                                            asum[m], 0, 0, 0);
      }
      __builtin_amdgcn_s_setprio(0);
      // ---- slice boundary ----
      if (t + 3 < NT)       vmw<2 * LT>();   // never 0 in steady state
      else if (t + 2 < NT)  vmw<LT>();
      else if (t + 1 < NT)  vmw<0>();
      __builtin_amdgcn_s_barrier();
      __builtin_amdgcn_sched_barrier(0);     // the ONLY pin: slice boundary
    } else {
      // ======== PIPE (r5 control) ========
      if (st) { stageA(nbuf); stageB(nbuf); }
#pragma unroll
      for (int m = 0; m < MF; ++m)
        af[m] = *(const short8*)&As[buf * ASL + (wr + m * 16 + fr) * 32 + rg];
#pragma unroll
      for (int n = 0; n < NF; ++n)
        bf[n] = *(const short8*)&Bs[buf * BSL + (wc + n * 16 + fr) * 32 + rg];
#pragma unroll
      for (int m = 0; m < MF; ++m)
#pragma unroll
        for (int n = 0; n < NF; ++n)
          acc[m][n] = __builtin_amdgcn_mfma_f32_16x16x32_bf16(af[m], bf[n],
                                                              acc[m][n], 0, 0, 0);
      if (EPI == EPI_PV) {
#pragma unroll
        for (int m = 0; m < MF; ++m)
          asum[m] = __builtin_amdgcn_mfma_f32_16x16x32_bf16(af[m], ones,
                                                            asum[m], 0, 0, 0);
      }
      __builtin_amdgcn_sched_barrier(0);
      if (t + 3 < NT)       vmw<2 * LT>();
      else if (t + 2 < NT)  vmw<LT>();
      else if (t + 1 < NT)  vmw<0>();
      __builtin_amdgcn_s_barrier();
      __builtin_amdgcn_sched_barrier(0);
    }
  }

  // ---- epilogue: C/D frag layout col=lane&15, row=(lane>>4)*4+j ----
  const int cr = hi * 4;
  const int cc = fr;
#pragma unroll
  for (int m = 0; m < MF; ++m) {
    const int row0 = bm + wr + m * 16 + cr;
#pragma unroll
    for (int n = 0; n < NF; ++n) {
      const int col = bn + wc + n * 16 + cc;
      const float bv = HAS_BIAS ? bias[col] : 0.f;
      if (EPI == EPI_F32) {
        float* D = (float*)Dv + (long long)bz * sD;
#pragma unroll
        for (int j = 0; j < 4; ++j)
          D[(long long)(row0 + j) * ldd + col] = acc[m][n][j] + bv;
      } else if (EPI == EPI_BF16) {
        unsigned short* D = (unsigned short*)Dv + (long long)bz * sD;
#pragma unroll
        for (int j = 0; j < 4; ++j)
          D[(long long)(row0 + j) * ldd + col] = f2bf((acc[m][n][j] + bv) * scale);
      } else if (EPI == EPI_BF16_TRANS) {
        unsigned short* D = (unsigned short*)Dv + (long long)bz * sD;
        ushort4 pk;
        pk.x = f2bf((acc[m][n][0] + bv) * scale);
        pk.y = f2bf((acc[m][n][1] + bv) * scale);
        pk.z = f2bf((acc[m][n][2] + bv) * scale);
        pk.w = f2bf((acc[m][n][3] + bv) * scale);
        *(ushort4*)&D[(long long)col * ldd + row0] = pk;
      } else if (EPI == EPI_EXP) {
        unsigned short* D = (unsigned short*)Dv + (long long)bz * sD;
#pragma unroll
        for (int j = 0; j < 4; ++j)
          D[(long long)(row0 + j) * ldd + col] = f2bf(__expf(acc[m][n][j]));
      } else {  // EPI_PV: normalize by MFMA-computed row-sum
        unsigned short* D = (unsigned short*)Dv + (long long)bz * sD;
#pragma unroll
        for (int j = 0; j < 4; ++j) {
          const float li = 1.f / asum[m][j];
          D[(long long)(row0 + j) * ldd + col] = f2bf(acc[m][n][j] * li);
        }
      }
    }
  }
}

extern "C" void kernel_launch(void* const* d_in, const int* in_sizes, int n_in,
                              void* d_out, int out_size, void* d_ws, size_t ws_size,
                              hipStream_t stream) {
  (void)in_sizes; (void)n_in; (void)out_size;
  const float* input  = (const float*)d_in[0];
  const float* memory = (const float*)d_in[1];
  const float* Wq = (const float*)d_in[2];
  const float* bq = (const float*)d_in[3];
  const float* Wk = (const float*)d_in[4];
  const float* bk = (const float*)d_in[5];
  const float* Wv = (const float*)d_in[6];
  const float* bv = (const float*)d_in[7];
  const float* Wo = (const float*)d_in[8];
  const float* bo = (const float*)d_in[9];
  float* out = (float*)d_out;

  const int S = 2048, C = 1024;
  const int CB = 4;                                // batches per attention chunk
  const long long BS = 16384;                      // 8 * 2048
  const long long N_IN = BS * C;                   // 16,777,216
  const long long N_W  = (long long)C * C;         // 1,048,576

  // ---- workspace layout (256B aligned), ~109 MiB ----
  char* p = (char*)d_ws;
  auto alloc = [&](size_t bytes) {
    char* r = p;
    p += (bytes + 255) & ~(size_t)255;
    return r;
  };
  unsigned short* wqb  = (unsigned short*)alloc(N_W * 2);
  unsigned short* wkb  = (unsigned short*)alloc(N_W * 2);
  unsigned short* wvb  = (unsigned short*)alloc(N_W * 2);
  unsigned short* wob  = (unsigned short*)alloc(N_W * 2);
  unsigned short* Qb   = (unsigned short*)alloc(N_IN * 2);   // [16384][1024]; later sel
  unsigned short* Kb   = (unsigned short*)alloc(N_IN * 2);   // [16384][1024]
  unsigned short* Xb   = (unsigned short*)alloc(N_IN * 2);   // memb, then Pt
  if ((size_t)(p - (char*)d_ws) > ws_size) return;

  // d_out scratch: [Vt bf16 16M | inb bf16 16M] = exactly 64 MiB
  unsigned short* Vt  = (unsigned short*)d_out;          // [1024][16384]
  unsigned short* inb = (unsigned short*)d_out + N_IN;   // [16384][1024]
  unsigned short* memb = Xb;
  unsigned short* Pt   = Xb;                             // alias after memb dead

  // ---- f32 -> bf16 ----
  wcvt_kernel<<<dim3(256, 4, 1), 256, 0, stream>>>(Wq, Wk, Wv, Wo,
                                                   wqb, wkb, wvb, wob,
                                                   (int)(N_W / 4));
  cvt2_kernel<<<dim3(2048, 2, 1), 256, 0, stream>>>(memory, input, memb, inb,
                                                    N_IN / 4);

  const float depth_scale = 0.03125f;  // 1024^-0.5

  // ---- projections: 256x256 tile, grid 256 ----
  // K-proj: PIPE (control)   Q-proj: PHASE (A/B pair, identical shape/EPI)
  gemm_kernel<256, 256, 2, 4, EPI_BF16, true, false><<<dim3(64, 4, 1), 512, 0, stream>>>(
      memb, wkb, bk, Kb, C, C, C, C, 0, 0, 0, 1.0f);
  gemm_kernel<256, 256, 2, 4, EPI_BF16_TRANS, true, false><<<dim3(64, 4, 1), 512, 0, stream>>>(
      memb, wvb, bv, Vt, C, C, C, (int)BS, 0, 0, 0, 1.0f);
  gemm_kernel<256, 256, 2, 4, EPI_BF16, true, true><<<dim3(64, 4, 1), 512, 0, stream>>>(
      inb, wqb, bq, Qb, C, C, C, C, 0, 0, 0, depth_scale);

  // ---- attention, CB=4 batches at a time (memb dead -> Pt) ----
  for (int c = 0; c < 8 / CB; ++c) {
    const long long qoff = (long long)c * CB * S * C;
    // P~ = exp(Q @ K^T): chunk0 PIPE, chunk1 PHASE
    if (c == 0)
      gemm_kernel<256, 256, 2, 4, EPI_EXP, false, false><<<dim3(8, 8, CB), 512, 0, stream>>>(
          Qb + qoff, Kb + qoff, nullptr, Pt,
          C, C, C, S, (long long)S * C, (long long)S * C, (long long)S * S, 1.0f);
    else
      gemm_kernel<256, 256, 2, 4, EPI_EXP, false, true><<<dim3(8, 8, CB), 512, 0, stream>>>(
          Qb + qoff, Kb + qoff, nullptr, Pt,
          C, C, C, S, (long long)S * C, (long long)S * C, (long long)S * S, 1.0f);
    // sel = (P~ @ V) / rowsum: chunk0 PIPE, chunk1 PHASE (128x256 tile)
    if (c == 0)
      gemm_kernel<128, 256, 2, 4, EPI_PV, false, false><<<dim3(16, 4, CB), 512, 0, stream>>>(
          Pt, Vt + (long long)c * CB * S, nullptr, Qb + qoff,
          S, S, (int)BS, C, (long long)S * S, (long long)S, (long long)S * C, 1.0f);
    else
      gemm_kernel<128, 256, 2, 4, EPI_PV, false, true><<<dim3(16, 4, CB), 512, 0, stream>>>(
          Pt, Vt + (long long)c * CB * S, nullptr, Qb + qoff,
          S, S, (int)BS, C, (long long)S * S, (long long)S, (long long)S * C, 1.0f);
  }

  // ---- out = sel @ Wo^T + bo -> f32 d_out (PHASE) ----
  gemm_kernel<256, 256, 2, 4, EPI_F32, true, true><<<dim3(64, 4, 1), 512, 0, stream>>>(
      Qb, wob, bo, out, C, C, C, C, 0, 0, 0, 1.0f);
}